// Round 12
// baseline (455.901 us; speedup 1.0000x reference)
//
#include <hip/hip_runtime.h>
#include <cmath>

// N=50000, E=800000, B=1, F=D=64, H=4, d=16, M=8.
// Edge kernels: lane = (head h=l>>4, edge-slot e=l&15). 16 edges/step/wave.
// KT[n] rows: per head h, [K_h(16f)|T_h(16f)] -> lane gathers contiguous 128B.
// Vfi[n] rows: per head h, [V_h(16f)|fi_h(8f)] -> lane gathers contiguous 96B.
// k_node is persistent (2048 blocks, wave-strided, uniform iteration count).

__device__ __forceinline__ float softplus_f(float z){
  return fmaxf(z, 0.f) + log1pf(__expf(-fabsf(z)));
}

// ---------------- K1: projections. mat0: Q f32 + WeQ; mat1: K->KT; mat2: T->KT; mat3: V->Vfi
__global__ __launch_bounds__(256) void k_proj(
    const float* __restrict__ x_src, const float* __restrict__ x_dst,
    const float* __restrict__ Wq, const float* __restrict__ Wk,
    const float* __restrict__ Wt, const float* __restrict__ Wv,
    const float* __restrict__ We,
    float* __restrict__ Qo, float* __restrict__ KTb,
    float* __restrict__ Vfib, float* __restrict__ WeQ, int N)
{
  int l   = threadIdx.x & 63;
  int mat = threadIdx.x >> 6;            // wave-uniform
  int n   = blockIdx.x * 64 + l;
  if (n >= N) return;
  const float* x = ((mat==0) ? x_dst : x_src) + (size_t)n*64;
  const float* W = (mat==0) ? Wq : (mat==1) ? Wk : (mat==2) ? Wt : Wv;
  const float4* W4  = (const float4*)W;
  const float4* We4 = (const float4*)We;

  float xr[64];
  const float4* x4 = (const float4*)x;
  #pragma unroll
  for (int i=0;i<16;i++){ float4 v=x4[i]; xr[4*i]=v.x; xr[4*i+1]=v.y; xr[4*i+2]=v.z; xr[4*i+3]=v.w; }

  float4* Q4   = (float4*)(Qo + (size_t)n*64);
  float4* KT4  = (float4*)KTb  + (size_t)n*32;
  float4* Vfi4 = (float4*)Vfib + (size_t)n*24;
  float weq0=0.f, weq1=0.f, weq2=0.f, weq3=0.f;
  #pragma unroll
  for (int jq=0;jq<16;jq++){
    float a0=0.f,a1=0.f,a2=0.f,a3=0.f;
    const float4* Wr4 = W4 + jq*64;
    #pragma unroll
    for (int f4=0;f4<16;f4++){
      float4 w0 = Wr4[f4], w1 = Wr4[16+f4], w2 = Wr4[32+f4], w3 = Wr4[48+f4];
      float x0=xr[4*f4], x1=xr[4*f4+1], x2=xr[4*f4+2], x3=xr[4*f4+3];
      a0=fmaf(w0.x,x0,a0); a0=fmaf(w0.y,x1,a0); a0=fmaf(w0.z,x2,a0); a0=fmaf(w0.w,x3,a0);
      a1=fmaf(w1.x,x0,a1); a1=fmaf(w1.y,x1,a1); a1=fmaf(w1.z,x2,a1); a1=fmaf(w1.w,x3,a1);
      a2=fmaf(w2.x,x0,a2); a2=fmaf(w2.y,x1,a2); a2=fmaf(w2.z,x2,a2); a2=fmaf(w2.w,x3,a2);
      a3=fmaf(w3.x,x0,a3); a3=fmaf(w3.y,x1,a3); a3=fmaf(w3.z,x2,a3); a3=fmaf(w3.w,x3,a3);
    }
    float4 r = make_float4(a0,a1,a2,a3);
    int hq = jq>>2, sq = jq&3;
    if (mat==0){
      Q4[jq] = r;
      float4 we = We4[jq];
      float ws = we.x*a0 + we.y*a1 + we.z*a2 + we.w*a3;
      if      (jq <  4) weq0 += ws;
      else if (jq <  8) weq1 += ws;
      else if (jq < 12) weq2 += ws;
      else              weq3 += ws;
    } else if (mat==1){
      KT4[hq*8 + sq] = r;                // K slot
    } else if (mat==2){
      KT4[hq*8 + 4 + sq] = r;            // T slot
    } else {
      Vfi4[hq*6 + sq] = r;               // V slot
    }
  }
  if (mat==0) *(float4*)(WeQ + (size_t)n*4) = make_float4(weq0,weq1,weq2,weq3);
}

// ---------------- CSR build
__global__ __launch_bounds__(256) void k_hist(const int* __restrict__ dst, int* __restrict__ deg, int E){
  int i = blockIdx.x*256 + threadIdx.x;
  if (i < E) atomicAdd(&deg[dst[i]], 1);
}

__global__ __launch_bounds__(1024) void k_scan1(const int* __restrict__ deg, int* __restrict__ rowptr,
                                                int* __restrict__ bsum, int N){
  __shared__ int sh[1024];
  int t = threadIdx.x;
  int i = blockIdx.x*1024 + t;
  int v = (i < N) ? deg[i] : 0;
  sh[t] = v; __syncthreads();
  int x = v;
  for (int off=1; off<1024; off<<=1){
    int y = (t >= off) ? sh[t-off] : 0;
    __syncthreads();
    x += y; sh[t] = x;
    __syncthreads();
  }
  if (i < N) rowptr[i] = x - v;
  if (t == 1023) bsum[blockIdx.x] = x;
}

__global__ __launch_bounds__(64) void k_scan2(int* __restrict__ bsum, int nb){
  int l = threadIdx.x;
  int v0 = (l < nb) ? bsum[l] : 0;
  int v = v0;
  for (int off=1; off<64; off<<=1){
    int y = __shfl_up(v, off);
    if (l >= off) v += y;
  }
  if (l < nb) bsum[l] = v - v0;
}

__global__ __launch_bounds__(1024) void k_scan3(int* __restrict__ rowptr, const int* __restrict__ bsum,
                                                int N, int E){
  int i = blockIdx.x*1024 + threadIdx.x;
  if (i < N) rowptr[i] += bsum[blockIdx.x];
  if (i == 0) rowptr[N] = E;
}

__global__ __launch_bounds__(256) void k_scatter(const int* __restrict__ dst, const int* __restrict__ src,
                                                 const float* __restrict__ ef,
                                                 const int* __restrict__ rowptr,
                                                 int* __restrict__ fill,
                                                 int2* __restrict__ sedge, int E){
  int i = blockIdx.x*256 + threadIdx.x;
  if (i < E){
    int d_ = dst[i];
    int pos = rowptr[d_] + atomicAdd(&fill[d_], 1);
    sedge[pos] = make_int2(src[i], __float_as_int(ef[i]));
  }
}

// ---------------- K5: persistent; per-dst-node: p=exp(e) + sum + g + MLP -> fi
#define KN_BLOCKS 2048
__global__ __launch_bounds__(256) void k_node(
    const float* __restrict__ Qb, const float* __restrict__ KTb,
    const float* __restrict__ WeQ, const float* __restrict__ t_in,
    const int* __restrict__ rowptr, const int2* __restrict__ sedge,
    const float* __restrict__ Wi, const float* __restrict__ bi,
    const float* __restrict__ wiw, const float* __restrict__ scale_i,
    float* __restrict__ es, float* __restrict__ esum,
    float* __restrict__ Vfib, int N)
{
  __shared__ float sWi[128*17];
  __shared__ float sbi[128];
  __shared__ float swiw[128];
  __shared__ float sscale[8];
  __shared__ float g_sh[4][4][17];
  __shared__ float tr[4][64][9];
  int tid = threadIdx.x;
  for (int i=tid; i<128*17; i+=256) sWi[i] = Wi[i];
  if (tid < 128){ sbi[tid] = bi[tid]; swiw[tid] = wiw[tid]; }
  if (tid < 8)  sscale[tid] = __expf(scale_i[tid]);
  __syncthreads();

  int w = tid>>6, l = tid&63;
  int h = l>>4, e = l&15;
  const int GW = KN_BLOCKS*4;
  int iters = (N + GW - 1) / GW;         // uniform across all waves

  for (int it=0; it<iters; ++it){
    int n = blockIdx.x*4 + w + it*GW;
    bool act = (n < N);

    float sacc = 0.f;
    float gacc[16];
    #pragma unroll
    for (int j=0;j<16;j++) gacc[j] = 0.f;
    int dg = 0;

    if (act){
      int row0 = rowptr[n];
      dg = rowptr[n+1] - row0;
      const float4* q4 = (const float4*)(Qb + (size_t)n*64 + (h<<4));
      float q[16];
      #pragma unroll
      for (int j=0;j<4;j++){
        float4 v = q4[j];
        q[4*j]=v.x*0.25f; q[4*j+1]=v.y*0.25f; q[4*j+2]=v.z*0.25f; q[4*j+3]=v.w*0.25f;
      }
      float weq = WeQ[n*4 + h] * 0.25f;

      int2 pv = (dg > 0 && e < dg) ? sedge[row0+e] : make_int2(0,0);
      for (int c0=0; c0<dg; c0+=16){
        int cnt = dg - c0;
        int2 cur = pv;
        if (c0+16 < dg && e < cnt-16) pv = sedge[row0+c0+16+e];
        int sn = cur.x;
        float efv = __int_as_float(cur.y);
        const float4* G4 = (const float4*)KTb + (size_t)sn*32 + (h<<3);  // contiguous 128B
        float4 k0=G4[0], k1=G4[1], k2=G4[2], k3=G4[3];
        float4 t0=G4[4], t1=G4[5], t2=G4[6], t3=G4[7];
        float p0 = fmaf(k0.x,q[0],  fmaf(k0.y,q[1],  fmaf(k0.z,q[2],  k0.w*q[3])));
        float p1 = fmaf(k1.x,q[4],  fmaf(k1.y,q[5],  fmaf(k1.z,q[6],  k1.w*q[7])));
        float p2 = fmaf(k2.x,q[8],  fmaf(k2.y,q[9],  fmaf(k2.z,q[10], k2.w*q[11])));
        float p3 = fmaf(k3.x,q[12], fmaf(k3.y,q[13], fmaf(k3.z,q[14], k3.w*q[15])));
        float dot = (p0+p1)+(p2+p3);
        float p = __expf(fmaf(efv, weq, dot));
        if (e >= cnt) p = 0.f;
        if (e < cnt)  es[(size_t)(row0+c0+e)*4 + h] = p;
        sacc += p;
        gacc[0] =fmaf(t0.x,p,gacc[0]);  gacc[1] =fmaf(t0.y,p,gacc[1]);
        gacc[2] =fmaf(t0.z,p,gacc[2]);  gacc[3] =fmaf(t0.w,p,gacc[3]);
        gacc[4] =fmaf(t1.x,p,gacc[4]);  gacc[5] =fmaf(t1.y,p,gacc[5]);
        gacc[6] =fmaf(t1.z,p,gacc[6]);  gacc[7] =fmaf(t1.w,p,gacc[7]);
        gacc[8] =fmaf(t2.x,p,gacc[8]);  gacc[9] =fmaf(t2.y,p,gacc[9]);
        gacc[10]=fmaf(t2.z,p,gacc[10]); gacc[11]=fmaf(t2.w,p,gacc[11]);
        gacc[12]=fmaf(t3.x,p,gacc[12]); gacc[13]=fmaf(t3.y,p,gacc[13]);
        gacc[14]=fmaf(t3.z,p,gacc[14]); gacc[15]=fmaf(t3.w,p,gacc[15]);
      }
    }

    sacc += __shfl_xor(sacc,1); sacc += __shfl_xor(sacc,2);
    sacc += __shfl_xor(sacc,4); sacc += __shfl_xor(sacc,8);
    if (act && e == 0) esum[n*4 + h] = sacc;
    float invs = (dg > 0) ? 1.f/sacc : 0.f;

    // two-pass transpose-reduce (dims 0..7 then 8..15)
    float gval = 0.f;
    *(float4*)&tr[w][l][0] = make_float4(gacc[0],gacc[1],gacc[2],gacc[3]);
    *(float4*)&tr[w][l][4] = make_float4(gacc[4],gacc[5],gacc[6],gacc[7]);
    __syncthreads();
    if (e < 8){
      float s = 0.f;
      #pragma unroll
      for (int ee=0; ee<16; ee++) s += tr[w][(h<<4)+ee][e];
      gval = s;
    }
    __syncthreads();
    *(float4*)&tr[w][l][0] = make_float4(gacc[8],gacc[9],gacc[10],gacc[11]);
    *(float4*)&tr[w][l][4] = make_float4(gacc[12],gacc[13],gacc[14],gacc[15]);
    __syncthreads();
    if (e >= 8){
      float s = 0.f;
      #pragma unroll
      for (int ee=0; ee<16; ee++) s += tr[w][(h<<4)+ee][e-8];
      gval = s;
    }
    if (act){
      g_sh[w][h][e] = gval * invs;
      if (l < 4) g_sh[w][l][16] = t_in[n];
    }
    __syncthreads();

    if (act){
      float wi1[17], wi2[17];
      #pragma unroll
      for (int j=0;j<17;j++){ wi1[j] = sWi[l*17 + j]; wi2[j] = sWi[(l+64)*17 + j]; }
      float b1 = sbi[l],  b2 = sbi[l+64];
      float wv1 = swiw[l], wv2 = swiw[l+64];
      float z1[4], z2[4];
      #pragma unroll
      for (int h2=0; h2<4; h2++){
        float a1=b1, a2=b2;
        #pragma unroll
        for (int j=0;j<17;j++){
          float inj = g_sh[w][h2][j];
          a1 = fmaf(wi1[j], inj, a1);
          a2 = fmaf(wi2[j], inj, a2);
        }
        float u1 = __fdividef(1.f, 1.f + __expf(-a1));
        float u2 = __fdividef(1.f, 1.f + __expf(-a2));
        float p1 = u1*wv1, p2 = u2*wv2;
        p1 += __shfl_xor(p1,1); p1 += __shfl_xor(p1,2); p1 += __shfl_xor(p1,4); p1 += __shfl_xor(p1,8);
        p2 += __shfl_xor(p2,1); p2 += __shfl_xor(p2,2); p2 += __shfl_xor(p2,4); p2 += __shfl_xor(p2,8);
        z1[h2] = p1; z2[h2] = p2;
      }
      if (e == 0){
        int m1 = h;
        float sc1 = sscale[m1], sc2 = sscale[m1+4];
        #pragma unroll
        for (int h2=0; h2<4; h2++){
          // fi slot inside Vfi row: head h2 at float offset h2*24 + 16
          Vfib[(size_t)n*96 + h2*24 + 16 + m1    ] = sc1*softplus_f(z1[h2]/sc1);
          Vfib[(size_t)n*96 + h2*24 + 16 + m1 + 4] = sc2*softplus_f(z2[h2]/sc2);
        }
      }
    }
    __syncthreads();
  }
}

// ---------------- K6: out[n] = x_dst[n] + (1/s) * sum_e V[src]*( (fi[src]·fm[n]) * p_e )
__global__ __launch_bounds__(256) void k_out(
    const float* __restrict__ Vfib,
    const float* __restrict__ es, const float* __restrict__ esum,
    const float* __restrict__ m_in, const float* __restrict__ x_dst,
    const int* __restrict__ rowptr, const int2* __restrict__ sedge,
    float* __restrict__ out, int N)
{
  __shared__ float tr[4][64][9];
  int tid = threadIdx.x;
  int w = tid>>6, l = tid&63;
  int h = l>>4, e = l&15;
  int n = blockIdx.x*4 + w;
  bool act = (n < N);

  float vacc[16];
  #pragma unroll
  for (int j=0;j<16;j++) vacc[j] = 0.f;
  float invs = 0.f;

  if (act){
    int row0 = rowptr[n];
    int dg = rowptr[n+1] - row0;
    float fm[8];
    const float4* m4 = (const float4*)(m_in + (size_t)n*8);
    float4 fma_=m4[0], fmb_=m4[1];
    fm[0]=fma_.x; fm[1]=fma_.y; fm[2]=fma_.z; fm[3]=fma_.w;
    fm[4]=fmb_.x; fm[5]=fmb_.y; fm[6]=fmb_.z; fm[7]=fmb_.w;
    float sh = esum[n*4 + h];
    invs = (dg > 0 && sh > 0.f) ? 1.f/sh : 0.f;

    int2 pv = (dg > 0 && e < dg) ? sedge[row0+e] : make_int2(0,0);
    for (int c0=0; c0<dg; c0+=16){
      int cnt = dg - c0;
      int sn = pv.x;
      if (c0+16 < dg && e < cnt-16) pv = sedge[row0+c0+16+e];
      float pe = (e < cnt) ? es[(size_t)(row0+c0+e)*4 + h] : 0.f;
      const float4* B4 = (const float4*)Vfib + (size_t)sn*24 + h*6;   // contiguous 96B
      float4 v0=B4[0], v1=B4[1], v2=B4[2], v3=B4[3], f0=B4[4], f1=B4[5];
      float dt = fmaf(f0.x,fm[0], fmaf(f0.y,fm[1], fmaf(f0.z,fm[2], fmaf(f0.w,fm[3],
                 fmaf(f1.x,fm[4], fmaf(f1.y,fm[5], fmaf(f1.z,fm[6], f1.w*fm[7])))))));
      float wgt = dt * pe;
      vacc[0] =fmaf(v0.x,wgt,vacc[0]);  vacc[1] =fmaf(v0.y,wgt,vacc[1]);
      vacc[2] =fmaf(v0.z,wgt,vacc[2]);  vacc[3] =fmaf(v0.w,wgt,vacc[3]);
      vacc[4] =fmaf(v1.x,wgt,vacc[4]);  vacc[5] =fmaf(v1.y,wgt,vacc[5]);
      vacc[6] =fmaf(v1.z,wgt,vacc[6]);  vacc[7] =fmaf(v1.w,wgt,vacc[7]);
      vacc[8] =fmaf(v2.x,wgt,vacc[8]);  vacc[9] =fmaf(v2.y,wgt,vacc[9]);
      vacc[10]=fmaf(v2.z,wgt,vacc[10]); vacc[11]=fmaf(v2.w,wgt,vacc[11]);
      vacc[12]=fmaf(v3.x,wgt,vacc[12]); vacc[13]=fmaf(v3.y,wgt,vacc[13]);
      vacc[14]=fmaf(v3.z,wgt,vacc[14]); vacc[15]=fmaf(v3.w,wgt,vacc[15]);
    }
  }

  float oval = 0.f;
  *(float4*)&tr[w][l][0] = make_float4(vacc[0],vacc[1],vacc[2],vacc[3]);
  *(float4*)&tr[w][l][4] = make_float4(vacc[4],vacc[5],vacc[6],vacc[7]);
  __syncthreads();
  if (e < 8){
    float s = 0.f;
    #pragma unroll
    for (int ee=0; ee<16; ee++) s += tr[w][(h<<4)+ee][e];
    oval = s;
  }
  __syncthreads();
  *(float4*)&tr[w][l][0] = make_float4(vacc[8],vacc[9],vacc[10],vacc[11]);
  *(float4*)&tr[w][l][4] = make_float4(vacc[12],vacc[13],vacc[14],vacc[15]);
  __syncthreads();
  if (e >= 8){
    float s = 0.f;
    #pragma unroll
    for (int ee=0; ee<16; ee++) s += tr[w][(h<<4)+ee][e-8];
    oval = s;
  }
  if (act)
    out[(size_t)n*64 + l] = fmaf(oval, invs, x_dst[(size_t)n*64 + l]);
}

extern "C" void kernel_launch(void* const* d_in, const int* in_sizes, int n_in,
                              void* d_out, int out_size, void* d_ws, size_t ws_size,
                              hipStream_t stream)
{
  const float* x_src = (const float*)d_in[0];
  const float* x_dst = (const float*)d_in[1];
  const float* t_in  = (const float*)d_in[2];
  const float* m_in  = (const float*)d_in[3];
  const float* ef    = (const float*)d_in[4];
  const float* Wq    = (const float*)d_in[5];
  const float* Wk    = (const float*)d_in[6];
  const float* Wv    = (const float*)d_in[7];
  const float* Wt    = (const float*)d_in[8];
  const float* We    = (const float*)d_in[9];
  const float* Wi    = (const float*)d_in[10];
  const float* bi    = (const float*)d_in[11];
  const float* wiw   = (const float*)d_in[12];
  const float* sci   = (const float*)d_in[13];
  const int*   src   = (const int*)d_in[14];
  const int*   dst   = (const int*)d_in[15];
  int N = in_sizes[0] / 64;
  int E = in_sizes[14];
  float* out = (float*)d_out;

  char* p = (char*)d_ws;
  auto alloc = [&](size_t bytes)->char*{ char* r = p; p += (bytes + 255) & ~(size_t)255; return r; };
  float* Qb   = (float*)alloc((size_t)N*64*4);
  float* KTb  = (float*)alloc((size_t)N*128*4);
  float* Vfib = (float*)alloc((size_t)N*96*4);
  float* WeQ  = (float*)alloc((size_t)N*4*4);
  float* esum = (float*)alloc((size_t)N*4*4);
  float* es   = (float*)alloc((size_t)E*4*4);
  int*   deg  = (int*)alloc((size_t)N*4);
  int*   fill = (int*)alloc((size_t)N*4);
  int*   rowp = (int*)alloc((size_t)(N+1)*4);
  int2*  sedge= (int2*)alloc((size_t)E*8);
  int    NB   = (N + 1023) / 1024;
  int*   bsum = (int*)alloc((size_t)NB*4);

  hipMemsetAsync(deg,  0, (size_t)N*4, stream);
  hipMemsetAsync(fill, 0, (size_t)N*4, stream);

  k_proj<<<(N+63)/64, 256, 0, stream>>>(x_src, x_dst, Wq, Wk, Wt, Wv, We, Qb, KTb, Vfib, WeQ, N);
  k_hist<<<(E+255)/256, 256, 0, stream>>>(dst, deg, E);
  k_scan1<<<NB, 1024, 0, stream>>>(deg, rowp, bsum, N);
  k_scan2<<<1, 64, 0, stream>>>(bsum, NB);
  k_scan3<<<NB, 1024, 0, stream>>>(rowp, bsum, N, E);
  k_scatter<<<(E+255)/256, 256, 0, stream>>>(dst, src, ef, rowp, fill, sedge, E);
  k_node<<<KN_BLOCKS, 256, 0, stream>>>(Qb, KTb, WeQ, t_in, rowp, sedge,
                                        Wi, bi, wiw, sci, es, esum, Vfib, N);
  k_out<<<(N+3)/4, 256, 0, stream>>>(Vfib, es, esum, m_in, x_dst, rowp, sedge, out, N);
}

// Round 13
// 454.760 us; speedup vs baseline: 1.0025x; 1.0025x over previous
//
#include <hip/hip_runtime.h>
#include <cmath>

// N=50000, E=800000, B=1, F=D=64, H=4, d=16, M=8.
// Edge kernels: lane = (head h=l>>4, edge-slot e=l&15). 16 edges/step/wave.
// k_node: two-pass LDS transpose (r11, no spills). k_out: fold16 in-register
// transpose, zero LDS (r10 — fastest measured k_out). k_proj: float4 W loads.

__device__ __forceinline__ float softplus_f(float z){
  return fmaxf(z, 0.f) + log1pf(__expf(-fabsf(z)));
}

// 16-lane transpose-reduce: lane e (=l&15) returns sum over its 16-lane group of v[dd=e].
__device__ __forceinline__ float fold16(float v[16], int e){
  #pragma unroll
  for (int k=0;k<16;k++) v[k] += __shfl_xor(v[k],1);
  float a[8]; bool s0 = (e&1);
  #pragma unroll
  for (int k=0;k<8;k++) a[k] = s0 ? v[2*k+1] : v[2*k];
  #pragma unroll
  for (int k=0;k<8;k++) a[k] += __shfl_xor(a[k],2);
  float b[4]; bool s1 = (e&2);
  #pragma unroll
  for (int k=0;k<4;k++) b[k] = s1 ? a[2*k+1] : a[2*k];
  #pragma unroll
  for (int k=0;k<4;k++) b[k] += __shfl_xor(b[k],4);
  float c[2]; bool s2 = (e&4);
  c[0] = s2 ? b[1] : b[0];
  c[1] = s2 ? b[3] : b[2];
  c[0] += __shfl_xor(c[0],8);
  c[1] += __shfl_xor(c[1],8);
  return (e&8) ? c[1] : c[0];
}

// ---------------- K1: projections Q,K,T,V (f32) + WeQ[h]; float4 W loads
__global__ __launch_bounds__(256) void k_proj(
    const float* __restrict__ x_src, const float* __restrict__ x_dst,
    const float* __restrict__ Wq, const float* __restrict__ Wk,
    const float* __restrict__ Wt, const float* __restrict__ Wv,
    const float* __restrict__ We,
    float* __restrict__ Qo, float* __restrict__ Ko,
    float* __restrict__ To, float* __restrict__ Vo,
    float* __restrict__ WeQ, int N)
{
  int l   = threadIdx.x & 63;
  int mat = threadIdx.x >> 6;            // wave-uniform
  int n   = blockIdx.x * 64 + l;
  if (n >= N) return;
  const float* x = ((mat==0) ? x_dst : x_src) + (size_t)n*64;
  const float* W = (mat==0) ? Wq : (mat==1) ? Wk : (mat==2) ? Wt : Wv;
  float*       O = (mat==0) ? Qo : (mat==1) ? Ko : (mat==2) ? To : Vo;
  const float4* W4  = (const float4*)W;
  const float4* We4 = (const float4*)We;

  float xr[64];
  const float4* x4 = (const float4*)x;
  #pragma unroll
  for (int i=0;i<16;i++){ float4 v=x4[i]; xr[4*i]=v.x; xr[4*i+1]=v.y; xr[4*i+2]=v.z; xr[4*i+3]=v.w; }

  float4* O4 = (float4*)(O + (size_t)n*64);
  float weq0=0.f, weq1=0.f, weq2=0.f, weq3=0.f;
  #pragma unroll
  for (int jq=0;jq<16;jq++){
    float a0=0.f,a1=0.f,a2=0.f,a3=0.f;
    const float4* Wr4 = W4 + jq*64;
    #pragma unroll
    for (int f4=0;f4<16;f4++){
      float4 w0 = Wr4[f4], w1 = Wr4[16+f4], w2 = Wr4[32+f4], w3 = Wr4[48+f4];
      float x0=xr[4*f4], x1=xr[4*f4+1], x2=xr[4*f4+2], x3=xr[4*f4+3];
      a0=fmaf(w0.x,x0,a0); a0=fmaf(w0.y,x1,a0); a0=fmaf(w0.z,x2,a0); a0=fmaf(w0.w,x3,a0);
      a1=fmaf(w1.x,x0,a1); a1=fmaf(w1.y,x1,a1); a1=fmaf(w1.z,x2,a1); a1=fmaf(w1.w,x3,a1);
      a2=fmaf(w2.x,x0,a2); a2=fmaf(w2.y,x1,a2); a2=fmaf(w2.z,x2,a2); a2=fmaf(w2.w,x3,a2);
      a3=fmaf(w3.x,x0,a3); a3=fmaf(w3.y,x1,a3); a3=fmaf(w3.z,x2,a3); a3=fmaf(w3.w,x3,a3);
    }
    O4[jq] = make_float4(a0,a1,a2,a3);
    if (mat==0){
      float4 we = We4[jq];
      float ws = we.x*a0 + we.y*a1 + we.z*a2 + we.w*a3;
      if      (jq <  4) weq0 += ws;
      else if (jq <  8) weq1 += ws;
      else if (jq < 12) weq2 += ws;
      else              weq3 += ws;
    }
  }
  if (mat==0) *(float4*)(WeQ + (size_t)n*4) = make_float4(weq0,weq1,weq2,weq3);
}

// ---------------- CSR build
__global__ __launch_bounds__(256) void k_hist(const int* __restrict__ dst, int* __restrict__ deg, int E){
  int i = blockIdx.x*256 + threadIdx.x;
  if (i < E) atomicAdd(&deg[dst[i]], 1);
}

__global__ __launch_bounds__(1024) void k_scan1(const int* __restrict__ deg, int* __restrict__ rowptr,
                                                int* __restrict__ bsum, int N){
  __shared__ int sh[1024];
  int t = threadIdx.x;
  int i = blockIdx.x*1024 + t;
  int v = (i < N) ? deg[i] : 0;
  sh[t] = v; __syncthreads();
  int x = v;
  for (int off=1; off<1024; off<<=1){
    int y = (t >= off) ? sh[t-off] : 0;
    __syncthreads();
    x += y; sh[t] = x;
    __syncthreads();
  }
  if (i < N) rowptr[i] = x - v;
  if (t == 1023) bsum[blockIdx.x] = x;
}

__global__ __launch_bounds__(64) void k_scan2(int* __restrict__ bsum, int nb){
  int l = threadIdx.x;
  int v0 = (l < nb) ? bsum[l] : 0;
  int v = v0;
  for (int off=1; off<64; off<<=1){
    int y = __shfl_up(v, off);
    if (l >= off) v += y;
  }
  if (l < nb) bsum[l] = v - v0;
}

__global__ __launch_bounds__(1024) void k_scan3(int* __restrict__ rowptr, const int* __restrict__ bsum,
                                                int N, int E){
  int i = blockIdx.x*1024 + threadIdx.x;
  if (i < N) rowptr[i] += bsum[blockIdx.x];
  if (i == 0) rowptr[N] = E;
}

// scatter packed edge payload {src, ef_bits} into CSR order
__global__ __launch_bounds__(256) void k_scatter(const int* __restrict__ dst, const int* __restrict__ src,
                                                 const float* __restrict__ ef,
                                                 const int* __restrict__ rowptr,
                                                 int* __restrict__ fill,
                                                 int2* __restrict__ sedge, int E){
  int i = blockIdx.x*256 + threadIdx.x;
  if (i < E){
    int d_ = dst[i];
    int pos = rowptr[d_] + atomicAdd(&fill[d_], 1);
    sedge[pos] = make_int2(src[i], __float_as_int(ef[i]));
  }
}

// ---------------- K5: per-dst-node: p=exp(e) + sum + g + MLP -> fi (r11 structure)
__global__ __launch_bounds__(256) void k_node(
    const float* __restrict__ Qb, const float* __restrict__ Kb, const float* __restrict__ Tb,
    const float* __restrict__ WeQ, const float* __restrict__ t_in,
    const int* __restrict__ rowptr, const int2* __restrict__ sedge,
    const float* __restrict__ Wi, const float* __restrict__ bi,
    const float* __restrict__ wiw, const float* __restrict__ scale_i,
    float* __restrict__ es, float* __restrict__ esum,
    float* __restrict__ fi_out, int N)
{
  __shared__ float sWi[128*17];
  __shared__ float sbi[128];
  __shared__ float swiw[128];
  __shared__ float sscale[8];
  __shared__ float g_sh[4][4][17];
  __shared__ float tr[4][64][9];
  int tid = threadIdx.x;
  for (int i=tid; i<128*17; i+=256) sWi[i] = Wi[i];
  if (tid < 128){ sbi[tid] = bi[tid]; swiw[tid] = wiw[tid]; }
  if (tid < 8)  sscale[tid] = __expf(scale_i[tid]);

  int w = tid>>6, l = tid&63;
  int h = l>>4, e = l&15;
  int n = blockIdx.x*4 + w;
  bool act = (n < N);

  float sacc = 0.f;
  float gacc[16];
  #pragma unroll
  for (int j=0;j<16;j++) gacc[j] = 0.f;
  int dg = 0;

  if (act){
    int row0 = rowptr[n];
    dg = rowptr[n+1] - row0;
    const float4* q4 = (const float4*)(Qb + (size_t)n*64 + (h<<4));
    float q[16];
    #pragma unroll
    for (int j=0;j<4;j++){
      float4 v = q4[j];
      q[4*j]=v.x*0.25f; q[4*j+1]=v.y*0.25f; q[4*j+2]=v.z*0.25f; q[4*j+3]=v.w*0.25f;
    }
    float weq = WeQ[n*4 + h] * 0.25f;

    int2 pv = (dg > 0 && e < dg) ? sedge[row0+e] : make_int2(0,0);
    for (int c0=0; c0<dg; c0+=16){
      int cnt = dg - c0;
      int2 cur = pv;
      if (c0+16 < dg && e < cnt-16) pv = sedge[row0+c0+16+e];   // prefetch next chunk
      int sn = cur.x;
      float efv = __int_as_float(cur.y);
      const float4* K4 = (const float4*)(Kb + ((size_t)sn<<6) + (h<<4));
      const float4* T4 = (const float4*)(Tb + ((size_t)sn<<6) + (h<<4));
      float4 k0=K4[0], k1=K4[1], k2=K4[2], k3=K4[3];
      float p0 = fmaf(k0.x,q[0],  fmaf(k0.y,q[1],  fmaf(k0.z,q[2],  k0.w*q[3])));
      float p1 = fmaf(k1.x,q[4],  fmaf(k1.y,q[5],  fmaf(k1.z,q[6],  k1.w*q[7])));
      float p2 = fmaf(k2.x,q[8],  fmaf(k2.y,q[9],  fmaf(k2.z,q[10], k2.w*q[11])));
      float p3 = fmaf(k3.x,q[12], fmaf(k3.y,q[13], fmaf(k3.z,q[14], k3.w*q[15])));
      float dot = (p0+p1)+(p2+p3);
      float p = __expf(fmaf(efv, weq, dot));
      if (e >= cnt) p = 0.f;
      if (e < cnt)  es[(size_t)(row0+c0+e)*4 + h] = p;
      sacc += p;
      float4 t0=T4[0], t1=T4[1], t2=T4[2], t3=T4[3];
      gacc[0] =fmaf(t0.x,p,gacc[0]);  gacc[1] =fmaf(t0.y,p,gacc[1]);
      gacc[2] =fmaf(t0.z,p,gacc[2]);  gacc[3] =fmaf(t0.w,p,gacc[3]);
      gacc[4] =fmaf(t1.x,p,gacc[4]);  gacc[5] =fmaf(t1.y,p,gacc[5]);
      gacc[6] =fmaf(t1.z,p,gacc[6]);  gacc[7] =fmaf(t1.w,p,gacc[7]);
      gacc[8] =fmaf(t2.x,p,gacc[8]);  gacc[9] =fmaf(t2.y,p,gacc[9]);
      gacc[10]=fmaf(t2.z,p,gacc[10]); gacc[11]=fmaf(t2.w,p,gacc[11]);
      gacc[12]=fmaf(t3.x,p,gacc[12]); gacc[13]=fmaf(t3.y,p,gacc[13]);
      gacc[14]=fmaf(t3.z,p,gacc[14]); gacc[15]=fmaf(t3.w,p,gacc[15]);
    }
  }

  // softmax denominator: reduce over the 16 edge-slot lanes
  sacc += __shfl_xor(sacc,1); sacc += __shfl_xor(sacc,2);
  sacc += __shfl_xor(sacc,4); sacc += __shfl_xor(sacc,8);
  if (act && e == 0) esum[n*4 + h] = sacc;
  float invs = (dg > 0) ? 1.f/sacc : 0.f;

  // two-pass transpose-reduce: pass 1 = dims 0..7, pass 2 = dims 8..15
  float gval = 0.f;
  *(float4*)&tr[w][l][0] = make_float4(gacc[0],gacc[1],gacc[2],gacc[3]);
  *(float4*)&tr[w][l][4] = make_float4(gacc[4],gacc[5],gacc[6],gacc[7]);
  __syncthreads();
  if (e < 8){
    float s = 0.f;
    #pragma unroll
    for (int ee=0; ee<16; ee++) s += tr[w][(h<<4)+ee][e];
    gval = s;
  }
  __syncthreads();
  *(float4*)&tr[w][l][0] = make_float4(gacc[8],gacc[9],gacc[10],gacc[11]);
  *(float4*)&tr[w][l][4] = make_float4(gacc[12],gacc[13],gacc[14],gacc[15]);
  __syncthreads();
  if (e >= 8){
    float s = 0.f;
    #pragma unroll
    for (int ee=0; ee<16; ee++) s += tr[w][(h<<4)+ee][e-8];
    gval = s;
  }
  if (act){
    g_sh[w][h][e] = gval * invs;
    if (l < 4) g_sh[w][l][16] = t_in[n];
  }
  __syncthreads();

  if (act){
    float wi1[17], wi2[17];
    #pragma unroll
    for (int j=0;j<17;j++){ wi1[j] = sWi[l*17 + j]; wi2[j] = sWi[(l+64)*17 + j]; }
    float b1 = sbi[l],  b2 = sbi[l+64];
    float wv1 = swiw[l], wv2 = swiw[l+64];
    float z1[4], z2[4];
    #pragma unroll
    for (int h2=0; h2<4; h2++){
      float a1=b1, a2=b2;
      #pragma unroll
      for (int j=0;j<17;j++){
        float inj = g_sh[w][h2][j];
        a1 = fmaf(wi1[j], inj, a1);
        a2 = fmaf(wi2[j], inj, a2);
      }
      float u1 = __fdividef(1.f, 1.f + __expf(-a1));
      float u2 = __fdividef(1.f, 1.f + __expf(-a2));
      float p1 = u1*wv1, p2 = u2*wv2;
      p1 += __shfl_xor(p1,1); p1 += __shfl_xor(p1,2); p1 += __shfl_xor(p1,4); p1 += __shfl_xor(p1,8);
      p2 += __shfl_xor(p2,1); p2 += __shfl_xor(p2,2); p2 += __shfl_xor(p2,4); p2 += __shfl_xor(p2,8);
      z1[h2] = p1; z2[h2] = p2;
    }
    if (e == 0){
      int m1 = h;
      float sc1 = sscale[m1], sc2 = sscale[m1+4];
      #pragma unroll
      for (int h2=0; h2<4; h2++){
        fi_out[(size_t)n*32 + h2*8 + m1    ] = sc1*softplus_f(z1[h2]/sc1);
        fi_out[(size_t)n*32 + h2*8 + m1 + 4] = sc2*softplus_f(z2[h2]/sc2);
      }
    }
  }
}

// ---------------- K6 (r10 fold16, no LDS): out[n] = x_dst[n] + (1/s)*sum_e V[src]*((fi[src]·fm[n])*p_e)
__global__ __launch_bounds__(256) void k_out(
    const float* __restrict__ Vb, const float* __restrict__ fi,
    const float* __restrict__ es, const float* __restrict__ esum,
    const float* __restrict__ m_in, const float* __restrict__ x_dst,
    const int* __restrict__ rowptr, const int2* __restrict__ sedge,
    float* __restrict__ out, int N)
{
  int tid = threadIdx.x;
  int w = tid>>6, l = tid&63;
  int h = l>>4, e = l&15;
  int n = blockIdx.x*4 + w;
  if (n >= N) return;

  float vacc[16];
  #pragma unroll
  for (int j=0;j<16;j++) vacc[j] = 0.f;

  int row0 = rowptr[n], dg = rowptr[n+1] - row0;
  float fm[8];
  const float4* m4 = (const float4*)(m_in + (size_t)n*8);
  float4 fma_=m4[0], fmb_=m4[1];
  fm[0]=fma_.x; fm[1]=fma_.y; fm[2]=fma_.z; fm[3]=fma_.w;
  fm[4]=fmb_.x; fm[5]=fmb_.y; fm[6]=fmb_.z; fm[7]=fmb_.w;
  float sh = esum[n*4 + h];
  float invs = (dg > 0 && sh > 0.f) ? 1.f/sh : 0.f;

  for (int c0=0; c0<dg; c0+=16){
    int cnt = dg - c0;
    int sn  = (e < cnt) ? sedge[row0+c0+e].x : 0;
    float pe = (e < cnt) ? es[(size_t)(row0+c0+e)*4 + h] : 0.f;
    const float4* F4 = (const float4*)(fi + ((size_t)sn<<5) + (h<<3));
    float4 f0=F4[0], f1=F4[1];
    float dt = fmaf(f0.x,fm[0], fmaf(f0.y,fm[1], fmaf(f0.z,fm[2], fmaf(f0.w,fm[3],
               fmaf(f1.x,fm[4], fmaf(f1.y,fm[5], fmaf(f1.z,fm[6], f1.w*fm[7])))))));
    float wgt = dt * pe;
    const float4* V4 = (const float4*)(Vb + ((size_t)sn<<6) + (h<<4));
    float4 v0=V4[0], v1=V4[1], v2=V4[2], v3=V4[3];
    vacc[0] =fmaf(v0.x,wgt,vacc[0]);  vacc[1] =fmaf(v0.y,wgt,vacc[1]);
    vacc[2] =fmaf(v0.z,wgt,vacc[2]);  vacc[3] =fmaf(v0.w,wgt,vacc[3]);
    vacc[4] =fmaf(v1.x,wgt,vacc[4]);  vacc[5] =fmaf(v1.y,wgt,vacc[5]);
    vacc[6] =fmaf(v1.z,wgt,vacc[6]);  vacc[7] =fmaf(v1.w,wgt,vacc[7]);
    vacc[8] =fmaf(v2.x,wgt,vacc[8]);  vacc[9] =fmaf(v2.y,wgt,vacc[9]);
    vacc[10]=fmaf(v2.z,wgt,vacc[10]); vacc[11]=fmaf(v2.w,wgt,vacc[11]);
    vacc[12]=fmaf(v3.x,wgt,vacc[12]); vacc[13]=fmaf(v3.y,wgt,vacc[13]);
    vacc[14]=fmaf(v3.z,wgt,vacc[14]); vacc[15]=fmaf(v3.w,wgt,vacc[15]);
  }

  float o = fold16(vacc, e);            // lane e holds out dd=e for head h
  out[(size_t)n*64 + l] = fmaf(o, invs, x_dst[(size_t)n*64 + l]);
}

extern "C" void kernel_launch(void* const* d_in, const int* in_sizes, int n_in,
                              void* d_out, int out_size, void* d_ws, size_t ws_size,
                              hipStream_t stream)
{
  const float* x_src = (const float*)d_in[0];
  const float* x_dst = (const float*)d_in[1];
  const float* t_in  = (const float*)d_in[2];
  const float* m_in  = (const float*)d_in[3];
  const float* ef    = (const float*)d_in[4];
  const float* Wq    = (const float*)d_in[5];
  const float* Wk    = (const float*)d_in[6];
  const float* Wv    = (const float*)d_in[7];
  const float* Wt    = (const float*)d_in[8];
  const float* We    = (const float*)d_in[9];
  const float* Wi    = (const float*)d_in[10];
  const float* bi    = (const float*)d_in[11];
  const float* wiw   = (const float*)d_in[12];
  const float* sci   = (const float*)d_in[13];
  const int*   src   = (const int*)d_in[14];
  const int*   dst   = (const int*)d_in[15];
  int N = in_sizes[0] / 64;
  int E = in_sizes[14];
  float* out = (float*)d_out;

  char* p = (char*)d_ws;
  auto alloc = [&](size_t bytes)->char*{ char* r = p; p += (bytes + 255) & ~(size_t)255; return r; };
  float* Qb   = (float*)alloc((size_t)N*64*4);
  float* Kb   = (float*)alloc((size_t)N*64*4);
  float* Tb   = (float*)alloc((size_t)N*64*4);
  float* Vb   = (float*)alloc((size_t)N*64*4);
  float* WeQ  = (float*)alloc((size_t)N*4*4);
  float* esum = (float*)alloc((size_t)N*4*4);
  float* fi   = (float*)alloc((size_t)N*32*4);
  float* es   = (float*)alloc((size_t)E*4*4);
  int*   deg  = (int*)alloc((size_t)N*4);
  int*   fill = (int*)alloc((size_t)N*4);
  int*   rowp = (int*)alloc((size_t)(N+1)*4);
  int2*  sedge= (int2*)alloc((size_t)E*8);
  int    NB   = (N + 1023) / 1024;
  int*   bsum = (int*)alloc((size_t)NB*4);

  hipMemsetAsync(deg,  0, (size_t)N*4, stream);
  hipMemsetAsync(fill, 0, (size_t)N*4, stream);

  k_proj<<<(N+63)/64, 256, 0, stream>>>(x_src, x_dst, Wq, Wk, Wt, Wv, We, Qb, Kb, Tb, Vb, WeQ, N);
  k_hist<<<(E+255)/256, 256, 0, stream>>>(dst, deg, E);
  k_scan1<<<NB, 1024, 0, stream>>>(deg, rowp, bsum, N);
  k_scan2<<<1, 64, 0, stream>>>(bsum, NB);
  k_scan3<<<NB, 1024, 0, stream>>>(rowp, bsum, N, E);
  k_scatter<<<(E+255)/256, 256, 0, stream>>>(dst, src, ef, rowp, fill, sedge, E);
  k_node<<<(N+3)/4, 256, 0, stream>>>(Qb, Kb, Tb, WeQ, t_in, rowp, sedge,
                                      Wi, bi, wiw, sci, es, esum, fi, N);
  k_out<<<(N+3)/4, 256, 0, stream>>>(Vb, fi, es, esum, m_in, x_dst, rowp, sedge, out, N);
}

// Round 15
// 371.380 us; speedup vs baseline: 1.2276x; 1.2245x over previous
//
#include <hip/hip_runtime.h>
#include <cmath>

// N=50000, E=800000, B=1, F=D=64, H=4, d=16, M=8.
// Edge kernels: lane = (head h=l>>4, edge-slot e=l&15). 16 edges/step/wave.
// Measured-best combo: k_proj = LDS-staged W (r10); k_node = two-pass LDS
// transpose (r11, 155us); k_out = two-pass LDS transpose (r11).

__device__ __forceinline__ float softplus_f(float z){
  return fmaxf(z, 0.f) + log1pf(__expf(-fabsf(z)));
}

// ---------------- K1: projections, W staged in LDS (broadcast ds_read_b128)
__global__ __launch_bounds__(256) void k_proj(
    const float* __restrict__ x_src, const float* __restrict__ x_dst,
    const float* __restrict__ Wq, const float* __restrict__ Wk,
    const float* __restrict__ Wt, const float* __restrict__ Wv,
    const float* __restrict__ We,
    float* __restrict__ Qo, float* __restrict__ Ko,
    float* __restrict__ To, float* __restrict__ Vo,
    float* __restrict__ WeQ, int N)
{
  __shared__ float sW[4*4096];
  int tid = threadIdx.x;
  {
    float4* dW = (float4*)sW;
    const float4* s0 = (const float4*)Wq;
    const float4* s1 = (const float4*)Wk;
    const float4* s2 = (const float4*)Wt;
    const float4* s3 = (const float4*)Wv;
    #pragma unroll
    for (int i=tid; i<1024; i+=256) dW[i]      = s0[i];
    #pragma unroll
    for (int i=tid; i<1024; i+=256) dW[1024+i] = s1[i];
    #pragma unroll
    for (int i=tid; i<1024; i+=256) dW[2048+i] = s2[i];
    #pragma unroll
    for (int i=tid; i<1024; i+=256) dW[3072+i] = s3[i];
  }
  __syncthreads();

  int l   = tid & 63;
  int mat = __builtin_amdgcn_readfirstlane(tid >> 6);   // assert wave-uniform
  int n   = blockIdx.x * 64 + l;
  if (n < N){
    const float* x = ((mat==0) ? x_dst : x_src) + (size_t)n*64;
    float*       O = (mat==0) ? Qo : (mat==1) ? Ko : (mat==2) ? To : Vo;
    const float4* Wm4 = (const float4*)(sW + (mat<<12));
    const float4* We4 = (const float4*)We;

    float xr[64];
    const float4* x4 = (const float4*)x;
    #pragma unroll
    for (int i=0;i<16;i++){ float4 v=x4[i]; xr[4*i]=v.x; xr[4*i+1]=v.y; xr[4*i+2]=v.z; xr[4*i+3]=v.w; }

    float4* O4 = (float4*)(O + (size_t)n*64);
    float weq0=0.f, weq1=0.f, weq2=0.f, weq3=0.f;
    #pragma unroll
    for (int jq=0;jq<16;jq++){
      float a0=0.f,a1=0.f,a2=0.f,a3=0.f;
      const float4* Wr4 = Wm4 + jq*64;   // rows jq*4..jq*4+3, 16 float4 each
      #pragma unroll
      for (int f4=0;f4<16;f4++){
        float4 w0 = Wr4[f4], w1 = Wr4[16+f4], w2 = Wr4[32+f4], w3 = Wr4[48+f4];
        float x0=xr[4*f4], x1=xr[4*f4+1], x2=xr[4*f4+2], x3=xr[4*f4+3];
        a0=fmaf(w0.x,x0,a0); a0=fmaf(w0.y,x1,a0); a0=fmaf(w0.z,x2,a0); a0=fmaf(w0.w,x3,a0);
        a1=fmaf(w1.x,x0,a1); a1=fmaf(w1.y,x1,a1); a1=fmaf(w1.z,x2,a1); a1=fmaf(w1.w,x3,a1);
        a2=fmaf(w2.x,x0,a2); a2=fmaf(w2.y,x1,a2); a2=fmaf(w2.z,x2,a2); a2=fmaf(w2.w,x3,a2);
        a3=fmaf(w3.x,x0,a3); a3=fmaf(w3.y,x1,a3); a3=fmaf(w3.z,x2,a3); a3=fmaf(w3.w,x3,a3);
      }
      O4[jq] = make_float4(a0,a1,a2,a3);
      if (mat==0){
        float4 we = We4[jq];
        float ws = we.x*a0 + we.y*a1 + we.z*a2 + we.w*a3;
        if      (jq <  4) weq0 += ws;
        else if (jq <  8) weq1 += ws;
        else if (jq < 12) weq2 += ws;
        else              weq3 += ws;
      }
    }
    if (mat==0) *(float4*)(WeQ + (size_t)n*4) = make_float4(weq0,weq1,weq2,weq3);
  }
}

// ---------------- CSR build
__global__ __launch_bounds__(256) void k_hist(const int* __restrict__ dst, int* __restrict__ deg, int E){
  int i = blockIdx.x*256 + threadIdx.x;
  if (i < E) atomicAdd(&deg[dst[i]], 1);
}

__global__ __launch_bounds__(1024) void k_scan1(const int* __restrict__ deg, int* __restrict__ rowptr,
                                                int* __restrict__ bsum, int N){
  __shared__ int sh[1024];
  int t = threadIdx.x;
  int i = blockIdx.x*1024 + t;
  int v = (i < N) ? deg[i] : 0;
  sh[t] = v; __syncthreads();
  int x = v;
  for (int off=1; off<1024; off<<=1){
    int y = (t >= off) ? sh[t-off] : 0;
    __syncthreads();
    x += y; sh[t] = x;
    __syncthreads();
  }
  if (i < N) rowptr[i] = x - v;
  if (t == 1023) bsum[blockIdx.x] = x;
}

__global__ __launch_bounds__(64) void k_scan2(int* __restrict__ bsum, int nb){
  int l = threadIdx.x;
  int v0 = (l < nb) ? bsum[l] : 0;
  int v = v0;
  for (int off=1; off<64; off<<=1){
    int y = __shfl_up(v, off);
    if (l >= off) v += y;
  }
  if (l < nb) bsum[l] = v - v0;
}

__global__ __launch_bounds__(1024) void k_scan3(int* __restrict__ rowptr, const int* __restrict__ bsum,
                                                int N, int E){
  int i = blockIdx.x*1024 + threadIdx.x;
  if (i < N) rowptr[i] += bsum[blockIdx.x];
  if (i == 0) rowptr[N] = E;
}

// scatter packed edge payload {src, ef_bits} into CSR order
__global__ __launch_bounds__(256) void k_scatter(const int* __restrict__ dst, const int* __restrict__ src,
                                                 const float* __restrict__ ef,
                                                 const int* __restrict__ rowptr,
                                                 int* __restrict__ fill,
                                                 int2* __restrict__ sedge, int E){
  int i = blockIdx.x*256 + threadIdx.x;
  if (i < E){
    int d_ = dst[i];
    int pos = rowptr[d_] + atomicAdd(&fill[d_], 1);
    sedge[pos] = make_int2(src[i], __float_as_int(ef[i]));
  }
}

// ---------------- K5: per-dst-node: p=exp(e) + sum + g + MLP -> fi (r11 structure)
__global__ __launch_bounds__(256) void k_node(
    const float* __restrict__ Qb, const float* __restrict__ Kb, const float* __restrict__ Tb,
    const float* __restrict__ WeQ, const float* __restrict__ t_in,
    const int* __restrict__ rowptr, const int2* __restrict__ sedge,
    const float* __restrict__ Wi, const float* __restrict__ bi,
    const float* __restrict__ wiw, const float* __restrict__ scale_i,
    float* __restrict__ es, float* __restrict__ esum,
    float* __restrict__ fi_out, int N)
{
  __shared__ float sWi[128*17];
  __shared__ float sbi[128];
  __shared__ float swiw[128];
  __shared__ float sscale[8];
  __shared__ float g_sh[4][4][17];
  __shared__ float tr[4][64][9];
  int tid = threadIdx.x;
  for (int i=tid; i<128*17; i+=256) sWi[i] = Wi[i];
  if (tid < 128){ sbi[tid] = bi[tid]; swiw[tid] = wiw[tid]; }
  if (tid < 8)  sscale[tid] = __expf(scale_i[tid]);

  int w = tid>>6, l = tid&63;
  int h = l>>4, e = l&15;
  int n = blockIdx.x*4 + w;
  bool act = (n < N);

  float sacc = 0.f;
  float gacc[16];
  #pragma unroll
  for (int j=0;j<16;j++) gacc[j] = 0.f;
  int dg = 0;

  if (act){
    int row0 = rowptr[n];
    dg = rowptr[n+1] - row0;
    const float4* q4 = (const float4*)(Qb + (size_t)n*64 + (h<<4));
    float q[16];
    #pragma unroll
    for (int j=0;j<4;j++){
      float4 v = q4[j];
      q[4*j]=v.x*0.25f; q[4*j+1]=v.y*0.25f; q[4*j+2]=v.z*0.25f; q[4*j+3]=v.w*0.25f;
    }
    float weq = WeQ[n*4 + h] * 0.25f;

    int2 pv = (dg > 0 && e < dg) ? sedge[row0+e] : make_int2(0,0);
    for (int c0=0; c0<dg; c0+=16){
      int cnt = dg - c0;
      int2 cur = pv;
      if (c0+16 < dg && e < cnt-16) pv = sedge[row0+c0+16+e];   // prefetch next chunk
      int sn = cur.x;
      float efv = __int_as_float(cur.y);
      const float4* K4 = (const float4*)(Kb + ((size_t)sn<<6) + (h<<4));
      const float4* T4 = (const float4*)(Tb + ((size_t)sn<<6) + (h<<4));
      float4 k0=K4[0], k1=K4[1], k2=K4[2], k3=K4[3];
      float p0 = fmaf(k0.x,q[0],  fmaf(k0.y,q[1],  fmaf(k0.z,q[2],  k0.w*q[3])));
      float p1 = fmaf(k1.x,q[4],  fmaf(k1.y,q[5],  fmaf(k1.z,q[6],  k1.w*q[7])));
      float p2 = fmaf(k2.x,q[8],  fmaf(k2.y,q[9],  fmaf(k2.z,q[10], k2.w*q[11])));
      float p3 = fmaf(k3.x,q[12], fmaf(k3.y,q[13], fmaf(k3.z,q[14], k3.w*q[15])));
      float dot = (p0+p1)+(p2+p3);
      float p = __expf(fmaf(efv, weq, dot));
      if (e >= cnt) p = 0.f;
      if (e < cnt)  es[(size_t)(row0+c0+e)*4 + h] = p;
      sacc += p;
      float4 t0=T4[0], t1=T4[1], t2=T4[2], t3=T4[3];
      gacc[0] =fmaf(t0.x,p,gacc[0]);  gacc[1] =fmaf(t0.y,p,gacc[1]);
      gacc[2] =fmaf(t0.z,p,gacc[2]);  gacc[3] =fmaf(t0.w,p,gacc[3]);
      gacc[4] =fmaf(t1.x,p,gacc[4]);  gacc[5] =fmaf(t1.y,p,gacc[5]);
      gacc[6] =fmaf(t1.z,p,gacc[6]);  gacc[7] =fmaf(t1.w,p,gacc[7]);
      gacc[8] =fmaf(t2.x,p,gacc[8]);  gacc[9] =fmaf(t2.y,p,gacc[9]);
      gacc[10]=fmaf(t2.z,p,gacc[10]); gacc[11]=fmaf(t2.w,p,gacc[11]);
      gacc[12]=fmaf(t3.x,p,gacc[12]); gacc[13]=fmaf(t3.y,p,gacc[13]);
      gacc[14]=fmaf(t3.z,p,gacc[14]); gacc[15]=fmaf(t3.w,p,gacc[15]);
    }
  }

  // softmax denominator: reduce over the 16 edge-slot lanes
  sacc += __shfl_xor(sacc,1); sacc += __shfl_xor(sacc,2);
  sacc += __shfl_xor(sacc,4); sacc += __shfl_xor(sacc,8);
  if (act && e == 0) esum[n*4 + h] = sacc;
  float invs = (dg > 0) ? 1.f/sacc : 0.f;

  // two-pass transpose-reduce: pass 1 = dims 0..7, pass 2 = dims 8..15
  float gval = 0.f;
  *(float4*)&tr[w][l][0] = make_float4(gacc[0],gacc[1],gacc[2],gacc[3]);
  *(float4*)&tr[w][l][4] = make_float4(gacc[4],gacc[5],gacc[6],gacc[7]);
  __syncthreads();
  if (e < 8){
    float s = 0.f;
    #pragma unroll
    for (int ee=0; ee<16; ee++) s += tr[w][(h<<4)+ee][e];
    gval = s;
  }
  __syncthreads();
  *(float4*)&tr[w][l][0] = make_float4(gacc[8],gacc[9],gacc[10],gacc[11]);
  *(float4*)&tr[w][l][4] = make_float4(gacc[12],gacc[13],gacc[14],gacc[15]);
  __syncthreads();
  if (e >= 8){
    float s = 0.f;
    #pragma unroll
    for (int ee=0; ee<16; ee++) s += tr[w][(h<<4)+ee][e-8];
    gval = s;
  }
  if (act){
    g_sh[w][h][e] = gval * invs;
    if (l < 4) g_sh[w][l][16] = t_in[n];
  }
  __syncthreads();

  if (act){
    float wi1[17], wi2[17];
    #pragma unroll
    for (int j=0;j<17;j++){ wi1[j] = sWi[l*17 + j]; wi2[j] = sWi[(l+64)*17 + j]; }
    float b1 = sbi[l],  b2 = sbi[l+64];
    float wv1 = swiw[l], wv2 = swiw[l+64];
    float z1[4], z2[4];
    #pragma unroll
    for (int h2=0; h2<4; h2++){
      float a1=b1, a2=b2;
      #pragma unroll
      for (int j=0;j<17;j++){
        float inj = g_sh[w][h2][j];
        a1 = fmaf(wi1[j], inj, a1);
        a2 = fmaf(wi2[j], inj, a2);
      }
      float u1 = __fdividef(1.f, 1.f + __expf(-a1));
      float u2 = __fdividef(1.f, 1.f + __expf(-a2));
      float p1 = u1*wv1, p2 = u2*wv2;
      p1 += __shfl_xor(p1,1); p1 += __shfl_xor(p1,2); p1 += __shfl_xor(p1,4); p1 += __shfl_xor(p1,8);
      p2 += __shfl_xor(p2,1); p2 += __shfl_xor(p2,2); p2 += __shfl_xor(p2,4); p2 += __shfl_xor(p2,8);
      z1[h2] = p1; z2[h2] = p2;
    }
    if (e == 0){
      int m1 = h;
      float sc1 = sscale[m1], sc2 = sscale[m1+4];
      #pragma unroll
      for (int h2=0; h2<4; h2++){
        fi_out[(size_t)n*32 + h2*8 + m1    ] = sc1*softplus_f(z1[h2]/sc1);
        fi_out[(size_t)n*32 + h2*8 + m1 + 4] = sc2*softplus_f(z2[h2]/sc2);
      }
    }
  }
}

// ---------------- K6 (two-pass LDS): out[n] = x_dst[n] + (1/s)*sum_e V[src]*((fi[src]·fm[n])*p_e)
__global__ __launch_bounds__(256) void k_out(
    const float* __restrict__ Vb, const float* __restrict__ fi,
    const float* __restrict__ es, const float* __restrict__ esum,
    const float* __restrict__ m_in, const float* __restrict__ x_dst,
    const int* __restrict__ rowptr, const int2* __restrict__ sedge,
    float* __restrict__ out, int N)
{
  __shared__ float tr[4][64][9];
  int tid = threadIdx.x;
  int w = tid>>6, l = tid&63;
  int h = l>>4, e = l&15;
  int n = blockIdx.x*4 + w;
  bool act = (n < N);

  float vacc[16];
  #pragma unroll
  for (int j=0;j<16;j++) vacc[j] = 0.f;
  float invs = 0.f;

  if (act){
    int row0 = rowptr[n];
    int dg = rowptr[n+1] - row0;
    float fm[8];
    const float4* m4 = (const float4*)(m_in + (size_t)n*8);
    float4 fma_=m4[0], fmb_=m4[1];
    fm[0]=fma_.x; fm[1]=fma_.y; fm[2]=fma_.z; fm[3]=fma_.w;
    fm[4]=fmb_.x; fm[5]=fmb_.y; fm[6]=fmb_.z; fm[7]=fmb_.w;
    float sh = esum[n*4 + h];
    invs = (dg > 0 && sh > 0.f) ? 1.f/sh : 0.f;

    int2 pv = (dg > 0 && e < dg) ? sedge[row0+e] : make_int2(0,0);
    for (int c0=0; c0<dg; c0+=16){
      int cnt = dg - c0;
      int sn = pv.x;
      if (c0+16 < dg && e < cnt-16) pv = sedge[row0+c0+16+e];   // prefetch next chunk
      float pe = (e < cnt) ? es[(size_t)(row0+c0+e)*4 + h] : 0.f;
      const float4* F4 = (const float4*)(fi + ((size_t)sn<<5) + (h<<3));
      float4 f0=F4[0], f1=F4[1];
      float dt = fmaf(f0.x,fm[0], fmaf(f0.y,fm[1], fmaf(f0.z,fm[2], fmaf(f0.w,fm[3],
                 fmaf(f1.x,fm[4], fmaf(f1.y,fm[5], fmaf(f1.z,fm[6], f1.w*fm[7])))))));
      float wgt = dt * pe;
      const float4* V4 = (const float4*)(Vb + ((size_t)sn<<6) + (h<<4));
      float4 v0=V4[0], v1=V4[1], v2=V4[2], v3=V4[3];
      vacc[0] =fmaf(v0.x,wgt,vacc[0]);  vacc[1] =fmaf(v0.y,wgt,vacc[1]);
      vacc[2] =fmaf(v0.z,wgt,vacc[2]);  vacc[3] =fmaf(v0.w,wgt,vacc[3]);
      vacc[4] =fmaf(v1.x,wgt,vacc[4]);  vacc[5] =fmaf(v1.y,wgt,vacc[5]);
      vacc[6] =fmaf(v1.z,wgt,vacc[6]);  vacc[7] =fmaf(v1.w,wgt,vacc[7]);
      vacc[8] =fmaf(v2.x,wgt,vacc[8]);  vacc[9] =fmaf(v2.y,wgt,vacc[9]);
      vacc[10]=fmaf(v2.z,wgt,vacc[10]); vacc[11]=fmaf(v2.w,wgt,vacc[11]);
      vacc[12]=fmaf(v3.x,wgt,vacc[12]); vacc[13]=fmaf(v3.y,wgt,vacc[13]);
      vacc[14]=fmaf(v3.z,wgt,vacc[14]); vacc[15]=fmaf(v3.w,wgt,vacc[15]);
    }
  }

  float oval = 0.f;
  *(float4*)&tr[w][l][0] = make_float4(vacc[0],vacc[1],vacc[2],vacc[3]);
  *(float4*)&tr[w][l][4] = make_float4(vacc[4],vacc[5],vacc[6],vacc[7]);
  __syncthreads();
  if (e < 8){
    float s = 0.f;
    #pragma unroll
    for (int ee=0; ee<16; ee++) s += tr[w][(h<<4)+ee][e];
    oval = s;
  }
  __syncthreads();
  *(float4*)&tr[w][l][0] = make_float4(vacc[8],vacc[9],vacc[10],vacc[11]);
  *(float4*)&tr[w][l][4] = make_float4(vacc[12],vacc[13],vacc[14],vacc[15]);
  __syncthreads();
  if (e >= 8){
    float s = 0.f;
    #pragma unroll
    for (int ee=0; ee<16; ee++) s += tr[w][(h<<4)+ee][e-8];
    oval = s;
  }
  if (act)
    out[(size_t)n*64 + l] = fmaf(oval, invs, x_dst[(size_t)n*64 + l]);
}

extern "C" void kernel_launch(void* const* d_in, const int* in_sizes, int n_in,
                              void* d_out, int out_size, void* d_ws, size_t ws_size,
                              hipStream_t stream)
{
  const float* x_src = (const float*)d_in[0];
  const float* x_dst = (const float*)d_in[1];
  const float* t_in  = (const float*)d_in[2];
  const float* m_in  = (const float*)d_in[3];
  const float* ef    = (const float*)d_in[4];
  const float* Wq    = (const float*)d_in[5];
  const float* Wk    = (const float*)d_in[6];
  const float* Wv    = (const float*)d_in[7];
  const float* Wt    = (const float*)d_in[8];
  const float* We    = (const float*)d_in[9];
  const float* Wi    = (const float*)d_in[10];
  const float* bi    = (const float*)d_in[11];
  const float* wiw   = (const float*)d_in[12];
  const float* sci   = (const float*)d_in[13];
  const int*   src   = (const int*)d_in[14];
  const int*   dst   = (const int*)d_in[15];
  int N = in_sizes[0] / 64;
  int E = in_sizes[14];
  float* out = (float*)d_out;

  char* p = (char*)d_ws;
  auto alloc = [&](size_t bytes)->char*{ char* r = p; p += (bytes + 255) & ~(size_t)255; return r; };
  float* Qb   = (float*)alloc((size_t)N*64*4);
  float* Kb   = (float*)alloc((size_t)N*64*4);
  float* Tb   = (float*)alloc((size_t)N*64*4);
  float* Vb   = (float*)alloc((size_t)N*64*4);
  float* WeQ  = (float*)alloc((size_t)N*4*4);
  float* esum = (float*)alloc((size_t)N*4*4);
  float* fi   = (float*)alloc((size_t)N*32*4);
  float* es   = (float*)alloc((size_t)E*4*4);
  int*   deg  = (int*)alloc((size_t)N*4);
  int*   fill = (int*)alloc((size_t)N*4);
  int*   rowp = (int*)alloc((size_t)(N+1)*4);
  int2*  sedge= (int2*)alloc((size_t)E*8);
  int    NB   = (N + 1023) / 1024;
  int*   bsum = (int*)alloc((size_t)NB*4);

  hipMemsetAsync(deg,  0, (size_t)N*4, stream);
  hipMemsetAsync(fill, 0, (size_t)N*4, stream);

  k_proj<<<(N+63)/64, 256, 0, stream>>>(x_src, x_dst, Wq, Wk, Wt, Wv, We, Qb, Kb, Tb, Vb, WeQ, N);
  k_hist<<<(E+255)/256, 256, 0, stream>>>(dst, deg, E);
  k_scan1<<<NB, 1024, 0, stream>>>(deg, rowp, bsum, N);
  k_scan2<<<1, 64, 0, stream>>>(bsum, NB);
  k_scan3<<<NB, 1024, 0, stream>>>(rowp, bsum, N, E);
  k_scatter<<<(E+255)/256, 256, 0, stream>>>(dst, src, ef, rowp, fill, sedge, E);
  k_node<<<(N+3)/4, 256, 0, stream>>>(Qb, Kb, Tb, WeQ, t_in, rowp, sedge,
                                      Wi, bi, wiw, sci, es, esum, fi, N);
  k_out<<<(N+3)/4, 256, 0, stream>>>(Vb, fi, es, esum, m_in, x_dst, rowp, sedge, out, N);
}